// Round 1
// baseline (85.552 us; speedup 1.0000x reference)
//
#include <hip/hip_runtime.h>
#include <cfloat>

#define NB 4096
#define NE 64
#define NH 512
#define TOPK 8

// Workspace layout (floats): [0..6] v_e (We @ Ws_e), [7..74] v_c (Wc @ Ws_c),
// [75] s_total = be@Ws_e + bc@Ws_c + bs
__global__ void precompute_kernel(const float* __restrict__ Wc,
                                  const float* __restrict__ bc,
                                  const float* __restrict__ We,
                                  const float* __restrict__ be,
                                  const float* __restrict__ Ws,
                                  const float* __restrict__ bs,
                                  float* __restrict__ ws) {
    int r = blockIdx.x;      // 0..75 : which reduction
    int lane = threadIdx.x;  // 0..63
    float partial = 0.f;
    if (r < 7) {
        const float* row = We + r * NH;
        for (int h = lane; h < NH; h += 64) partial += row[h] * Ws[h];
    } else if (r < 75) {
        const float* row = Wc + (r - 7) * NH;
        for (int h = lane; h < NH; h += 64) partial += row[h] * Ws[NH + h];
    } else {
        for (int h = lane; h < NH; h += 64)
            partial += be[h] * Ws[h] + bc[h] * Ws[NH + h];
    }
    for (int off = 32; off; off >>= 1) partial += __shfl_xor(partial, off);
    if (lane == 0) {
        if (r == 75) partial += bs[0];
        ws[r] = partial;
    }
}

// One 64-lane wave per batch row; lane e owns expert e.
__global__ __launch_bounds__(256) void router_kernel(
    const float* __restrict__ x_context,  // (B,68)
    const float* __restrict__ x_q,        // (B,E,3)
    const float* __restrict__ x_r,        // (B,E,2)
    const float* __restrict__ x_k,        // (B,E,2)
    const float* __restrict__ ws,         // 76 precomputed floats
    float* __restrict__ out_action,       // (B,3)
    float* __restrict__ out_gate,         // (B,E)
    float* __restrict__ out_logits)       // (B,E)
{
    __shared__ float sws[76];
    int t = threadIdx.x;
    if (t < 76) sws[t] = ws[t];
    __syncthreads();

    int lane = t & 63;
    int b = blockIdx.x * 4 + (t >> 6);

    // context contribution: dot(x_context[b, 0:68], v_c) via wave reduction
    const float* xc = x_context + (size_t)b * 68;
    float cb = xc[lane] * sws[7 + lane];
    if (lane < 4) cb += xc[64 + lane] * sws[7 + 64 + lane];
    for (int off = 32; off; off >>= 1) cb += __shfl_xor(cb, off);

    size_t be_idx = (size_t)b * NE + lane;
    float q0 = x_q[be_idx * 3 + 0];
    float q1 = x_q[be_idx * 3 + 1];
    float q2 = x_q[be_idx * 3 + 2];
    float r0 = x_r[be_idx * 2 + 0];
    float r1 = x_r[be_idx * 2 + 1];
    float k0 = x_k[be_idx * 2 + 0];
    float k1 = x_k[be_idx * 2 + 1];

    float logit = q0 * sws[0] + q1 * sws[1] + q2 * sws[2]
                + r0 * sws[3] + r1 * sws[4]
                + k0 * sws[5] + k1 * sws[6]
                + sws[75] + cb;

    out_logits[be_idx] = logit;

    // top-8 via 8 rounds of butterfly argmax (ties -> smaller index, like lax.top_k)
    float work = logit;
    bool sel = false;
    float m = 0.f;
    #pragma unroll
    for (int k = 0; k < TOPK; ++k) {
        float bv = work;
        int bi = lane;
        for (int off = 32; off; off >>= 1) {
            float ov = __shfl_xor(bv, off);
            int oi = __shfl_xor(bi, off);
            if (ov > bv || (ov == bv && oi < bi)) { bv = ov; bi = oi; }
        }
        if (k == 0) m = bv;
        if (lane == bi) { sel = true; work = -FLT_MAX; }
    }

    // softmax over selected lanes (non-selected are exactly 0, matching exp(-inf))
    float e = sel ? __expf(logit - m) : 0.f;
    float denom = e;
    for (int off = 32; off; off >>= 1) denom += __shfl_xor(denom, off);
    float gate = e / denom;
    out_gate[be_idx] = gate;

    // action_logits[b,a] = sum_e gate[e] * q[e][a]
    float a0 = gate * q0, a1 = gate * q1, a2 = gate * q2;
    for (int off = 32; off; off >>= 1) {
        a0 += __shfl_xor(a0, off);
        a1 += __shfl_xor(a1, off);
        a2 += __shfl_xor(a2, off);
    }
    if (lane == 0) {
        out_action[(size_t)b * 3 + 0] = a0;
        out_action[(size_t)b * 3 + 1] = a1;
        out_action[(size_t)b * 3 + 2] = a2;
    }
}

extern "C" void kernel_launch(void* const* d_in, const int* in_sizes, int n_in,
                              void* d_out, int out_size, void* d_ws, size_t ws_size,
                              hipStream_t stream) {
    const float* x_context = (const float*)d_in[0];
    const float* x_q       = (const float*)d_in[1];
    const float* x_r       = (const float*)d_in[2];
    const float* x_k       = (const float*)d_in[3];
    const float* Wc        = (const float*)d_in[4];
    const float* bc        = (const float*)d_in[5];
    const float* We        = (const float*)d_in[6];
    const float* be        = (const float*)d_in[7];
    const float* Ws        = (const float*)d_in[8];
    const float* bs        = (const float*)d_in[9];

    float* out        = (float*)d_out;
    float* out_action = out;                    // B*3
    float* out_gate   = out + NB * 3;           // B*E
    float* out_logits = out + NB * 3 + NB * NE; // B*E
    float* wsf = (float*)d_ws;

    precompute_kernel<<<76, 64, 0, stream>>>(Wc, bc, We, be, Ws, bs, wsf);
    router_kernel<<<NB / 4, 256, 0, stream>>>(x_context, x_q, x_r, x_k, wsf,
                                              out_action, out_gate, out_logits);
}